// Round 10
// baseline (200.491 us; speedup 1.0000x reference)
//
#include <hip/hip_runtime.h>

#define TD 256  // feature dim

typedef __attribute__((ext_vector_type(8))) short short8;
typedef __attribute__((ext_vector_type(8))) unsigned short ushort8;
typedef __attribute__((ext_vector_type(4))) float f32x4;

__device__ inline unsigned short f2bf(float f) {
  unsigned u = __float_as_uint(f);
  u = u + 0x7fffu + ((u >> 16) & 1u);  // round-to-nearest-even
  return (unsigned short)(u >> 16);
}
__device__ inline float bf2f(unsigned short h) {
  return __uint_as_float(((unsigned)h) << 16);
}

// ===========================================================================
// Prologue mega-kernel: hist | x->bf16 | Wq,Wk row-major bf16 | W0,W1,Wv^T bf16
// ===========================================================================
__global__ __launch_bounds__(256) void prologue_kernel(
    const int* __restrict__ ei, int E1, const int* __restrict__ ei2, int E2,
    int* __restrict__ deg1, int* __restrict__ deg2,
    const float* __restrict__ x, unsigned short* __restrict__ xb, long total8,
    const float* __restrict__ Wq, const float* __restrict__ Wk,
    unsigned short* __restrict__ wqb, unsigned short* __restrict__ wkb,
    const float* __restrict__ W0, const float* __restrict__ W1,
    const float* __restrict__ Wv, unsigned short* __restrict__ wt,
    int nbH, int nbX) {
  int b = blockIdx.x;
  if (b < nbH) {
    int stride = nbH * 256;
    int Emax = max(E1, E2);
    for (int i = b * 256 + threadIdx.x; i < Emax; i += stride) {
      if (i < E1) atomicAdd(&deg1[ei[E1 + i]], 1);
      if (i < E2) atomicAdd(&deg2[ei2[E2 + i]], 1);
    }
  } else if (b < nbH + nbX) {
    long t = (long)(b - nbH) * 256 + threadIdx.x;
    if (t >= total8) return;
    const float4 f0 = *reinterpret_cast<const float4*>(x + t * 8);
    const float4 f1 = *reinterpret_cast<const float4*>(x + t * 8 + 4);
    ushort8 o;
    o[0] = f2bf(f0.x); o[1] = f2bf(f0.y); o[2] = f2bf(f0.z); o[3] = f2bf(f0.w);
    o[4] = f2bf(f1.x); o[5] = f2bf(f1.y); o[6] = f2bf(f1.z); o[7] = f2bf(f1.w);
    *reinterpret_cast<ushort8*>(xb + t * 8) = o;
  } else if (b < nbH + nbX + 64) {
    int t = (b - nbH - nbX) * 256 + threadIdx.x;  // 0..16383
    const float* src = (t < 8192) ? Wq : Wk;
    unsigned short* dst = (t < 8192) ? wqb : wkb;
    int o = (t & 8191) * 8;
    ushort8 r;
#pragma unroll
    for (int j = 0; j < 8; j++) r[j] = f2bf(src[o + j]);
    *reinterpret_cast<ushort8*>(dst + o) = r;
  } else {
    int b2 = b - nbH - nbX - 64;  // 0..767
    int m = b2 >> 8;
    int n = b2 & 255;
    int k = threadIdx.x;
    const float* W = m == 0 ? W0 : m == 1 ? W1 : Wv;
    wt[m * 65536 + n * 256 + k] = f2bf(W[k * 256 + n]);
  }
}

// ===========================================================================
// scan phase A (blocks 0..511) + gemmG (blocks 512..515)
// ===========================================================================
__global__ __launch_bounds__(256) void scanA_gemmG_kernel(
    const int* __restrict__ deg1, const int* __restrict__ deg2, int N,
    int* __restrict__ bsum,
    const unsigned short* __restrict__ wqb, const unsigned short* __restrict__ wkb,
    unsigned short* __restrict__ gt) {
  if (blockIdx.x < 512) {
    int arr = blockIdx.x >> 8;
    int b = blockIdx.x & 255;
    const int* deg = arr ? deg2 : deg1;
    int i = b * 256 + threadIdx.x;
    int v = (i < N) ? deg[i] : 0;
#pragma unroll
    for (int m = 1; m < 64; m <<= 1) v += __shfl_xor(v, m, 64);
    __shared__ int wsum[4];
    if ((threadIdx.x & 63) == 0) wsum[threadIdx.x >> 6] = v;
    __syncthreads();
    if (threadIdx.x == 0)
      bsum[blockIdx.x] = wsum[0] + wsum[1] + wsum[2] + wsum[3];
    return;
  }
  const int t = (blockIdx.x - 512) * 4 + (threadIdx.x >> 6);
  const int l = threadIdx.x & 63;
  const int a0 = (t >> 2) * 64;
  const int b0 = (t & 3) * 64;
  const int lc = l & 15;
  const int lk = l >> 4;
  f32x4 acc[4][4] = {};
#pragma unroll
  for (int ks = 0; ks < 256; ks += 32) {
    const int ko = ks + lk * 8;
    short8 a[4], b[4];
#pragma unroll
    for (int m = 0; m < 4; m++)
      a[m] = *reinterpret_cast<const short8*>(wqb + (a0 + m * 16 + lc) * 256 + ko);
#pragma unroll
    for (int n = 0; n < 4; n++)
      b[n] = *reinterpret_cast<const short8*>(wkb + (b0 + n * 16 + lc) * 256 + ko);
#pragma unroll
    for (int m = 0; m < 4; m++)
#pragma unroll
      for (int n = 0; n < 4; n++)
        acc[m][n] =
            __builtin_amdgcn_mfma_f32_16x16x32_bf16(a[m], b[n], acc[m][n], 0, 0, 0);
  }
#pragma unroll
  for (int m = 0; m < 4; m++)
#pragma unroll
    for (int n = 0; n < 4; n++)
#pragma unroll
      for (int j = 0; j < 4; j++) {
        int a = a0 + m * 16 + lk * 4 + j;
        int b = b0 + n * 16 + lc;
        gt[b * 256 + a] = f2bf(acc[m][n][j]);
      }
}

// ===========================================================================
// scan_fill with in-block bsum prefix.  grid = 512.  bsum = RAW block sums.
// ===========================================================================
__global__ __launch_bounds__(256) void scan_fill_kernel(
    const int* __restrict__ deg1, const int* __restrict__ deg2,
    const int* __restrict__ bsum, int N,
    int* __restrict__ off1, int* __restrict__ cur1,
    int* __restrict__ off2, int* __restrict__ cur2) {
  int arr = blockIdx.x >> 8;
  int b = blockIdx.x & 255;
  const int* deg = arr ? deg2 : deg1;
  int* off = arr ? off2 : off1;
  int* cur = arr ? cur2 : cur1;
  const int t = threadIdx.x;

  __shared__ int redp[4], redt[4];
  int sval = bsum[arr * 256 + t];
  int pv = (t < b) ? sval : 0;
  int tv = sval;
#pragma unroll
  for (int m = 1; m < 64; m <<= 1) {
    pv += __shfl_xor(pv, m, 64);
    tv += __shfl_xor(tv, m, 64);
  }
  if ((t & 63) == 0) { redp[t >> 6] = pv; redt[t >> 6] = tv; }
  __syncthreads();
  int prefix = redp[0] + redp[1] + redp[2] + redp[3];
  int total = redt[0] + redt[1] + redt[2] + redt[3];
  if (b == 255 && t == 0) off[N] = total;

  int i = b * 256 + t;
  __shared__ int sm[256];
  int v = (i < N) ? deg[i] : 0;
  sm[t] = v;
  __syncthreads();
  for (int d = 1; d < 256; d <<= 1) {
    int val = (t >= d) ? sm[t - d] : 0;
    __syncthreads();
    sm[t] += val;
    __syncthreads();
  }
  int e = sm[t] - v + prefix;
  if (i < N) {
    off[i] = e;
    cur[i] = e;
  }
}

// ===========================================================================
// Double-buffered LDS MFMA GEMM body, tile 128x256, BK=32, 512 thr = 8 waves.
//   MODE 0: q' = xb @ Gt                    (K=256, bf16 -> qb)
//   MODE 1: out = xb@W0 + aggb@W1 + tb@Wv   (K=768 segmented, fp32 out)
// T3-minimum schedule: stage(t+1) issued before compute(t), ONE barrier/step.
// 2-bit XOR swizzle: slot ^= (row&3)^((row>>2)&3)  (2-way bank alias = free).
// ===========================================================================
template <int MODE>
__device__ __forceinline__ void stage_step(
    const unsigned short* Ap, const unsigned short* Bp, int m0, int ks, int M,
    int t, unsigned short* sAbuf, unsigned short* sBbuf) {
  const int r = t >> 2, s = t & 3;
  {
    int g = (s ^ (r & 3) ^ ((r >> 2) & 3)) & 3;
    int gr = m0 + r;
    if (gr >= M) gr = M - 1;
    __builtin_amdgcn_global_load_lds(
        (const __attribute__((address_space(1))) void*)(Ap + (size_t)gr * TD + ks + g * 8),
        (__attribute__((address_space(3))) void*)(sAbuf + r * 32 + s * 8), 16, 0, 0);
  }
#pragma unroll
  for (int i = 0; i < 2; i++) {
    int rb = r + i * 128;
    int g = (s ^ (rb & 3) ^ ((rb >> 2) & 3)) & 3;
    __builtin_amdgcn_global_load_lds(
        (const __attribute__((address_space(1))) void*)(Bp + (size_t)rb * TD + ks + g * 8),
        (__attribute__((address_space(3))) void*)(sBbuf + rb * 32 + s * 8), 16, 0, 0);
  }
}

template <int MODE>
__device__ __forceinline__ void gemm_body(
    int bid, const unsigned short* __restrict__ xb,
    const unsigned short* __restrict__ aggb, const unsigned short* __restrict__ tb,
    const unsigned short* __restrict__ wt, const unsigned short* __restrict__ gt,
    float* __restrict__ out, unsigned short* __restrict__ qb, int M,
    unsigned short* sA, unsigned short* sB) {
  const int m0 = bid * 128;
  const int tid = threadIdx.x;
  const int w = tid >> 6, l = tid & 63;
  const int wr = w >> 2, wc = w & 3;  // 2x4 wave grid, 64x64 each

  f32x4 acc[4][4] = {};

  const int NSTEP = (MODE == 0) ? 8 : 24;

  // resolve source pointers for a K-step
  const unsigned short* Ap;
  const unsigned short* Bp;
  int ks;
#define SRCS(step)                                                     \
  {                                                                    \
    int k0 = (step) * 32;                                              \
    if (MODE == 0) { Ap = xb; Bp = gt; ks = k0; }                      \
    else {                                                             \
      int seg = k0 >> 8;                                               \
      Ap = seg == 0 ? xb : seg == 1 ? aggb : tb;                       \
      Bp = wt + seg * 65536;                                           \
      ks = k0 & 255;                                                   \
    }                                                                  \
  }

  SRCS(0);
  stage_step<MODE>(Ap, Bp, m0, ks, M, tid, sA, sB);
  __syncthreads();

  int cur = 0;
  for (int step = 0; step < NSTEP; ++step) {
    if (step + 1 < NSTEP) {
      SRCS(step + 1);
      stage_step<MODE>(Ap, Bp, m0, ks, M, tid, sA + (cur ^ 1) * 4096,
                       sB + (cur ^ 1) * 8192);
    }
    const unsigned short* cA = sA + cur * 4096;
    const unsigned short* cB = sB + cur * 8192;
    short8 a[4], b[4];
#pragma unroll
    for (int m = 0; m < 4; m++) {
      int R = wr * 64 + m * 16 + (l & 15);
      int slot = ((l >> 4) ^ (R & 3) ^ ((R >> 2) & 3)) & 3;
      a[m] = *reinterpret_cast<const short8*>(&cA[R * 32 + slot * 8]);
    }
#pragma unroll
    for (int n = 0; n < 4; n++) {
      int R = wc * 64 + n * 16 + (l & 15);
      int slot = ((l >> 4) ^ (R & 3) ^ ((R >> 2) & 3)) & 3;
      b[n] = *reinterpret_cast<const short8*>(&cB[R * 32 + slot * 8]);
    }
#pragma unroll
    for (int m = 0; m < 4; m++)
#pragma unroll
      for (int n = 0; n < 4; n++)
        acc[m][n] =
            __builtin_amdgcn_mfma_f32_16x16x32_bf16(a[m], b[n], acc[m][n], 0, 0, 0);
    __syncthreads();
    cur ^= 1;
  }
#undef SRCS

  // ---- store: row = m0 + wr*64 + m*16 + (l>>4)*4 + j, col = wc*64 + n*16 + (l&15)
  if (MODE == 1) {
#pragma unroll
    for (int m = 0; m < 4; m++)
#pragma unroll
      for (int n = 0; n < 4; n++)
#pragma unroll
        for (int j = 0; j < 4; j++) {
          int r = m0 + wr * 64 + m * 16 + (l >> 4) * 4 + j;
          if (r < M)
            out[(size_t)r * TD + wc * 64 + n * 16 + (l & 15)] = acc[m][n][j];
        }
  } else {
#pragma unroll
    for (int m = 0; m < 4; m++)
#pragma unroll
      for (int n = 0; n < 4; n++)
#pragma unroll
        for (int j = 0; j < 4; j++) {
          int r = m0 + wr * 64 + m * 16 + (l >> 4) * 4 + j;
          if (r < M)
            qb[(size_t)r * TD + wc * 64 + n * 16 + (l & 15)] =
                f2bf(acc[m][n][j]);
        }
  }
}

// ===========================================================================
// Merged: blocks [0,FB) do CSR fill (both graphs); [FB, FB+gblk) do gemm0.
// ===========================================================================
__global__ __launch_bounds__(512) void fill_gemm0_kernel(
    const int* __restrict__ ei, int E1, const int* __restrict__ ei2, int E2,
    int* __restrict__ cur1, int* __restrict__ cur2,
    int* __restrict__ csr1, int* __restrict__ csr2,
    const unsigned short* __restrict__ xb, const unsigned short* __restrict__ gt,
    unsigned short* __restrict__ qb, int M, int FB) {
  __shared__ __align__(16) unsigned short sA[2 * 128 * 32];
  __shared__ __align__(16) unsigned short sB[2 * 256 * 32];
  if (blockIdx.x < FB) {
    int stride = FB * 512;
    int Emax = max(E1, E2);
    for (int i = blockIdx.x * 512 + threadIdx.x; i < Emax; i += stride) {
      if (i < E1) {
        int d = ei[E1 + i];
        int p = atomicAdd(&cur1[d], 1);
        csr1[p] = ei[i];
      }
      if (i < E2) {
        int d = ei2[E2 + i];
        int p = atomicAdd(&cur2[d], 1);
        csr2[p] = ei2[i];
      }
    }
    return;
  }
  gemm_body<0>(blockIdx.x - FB, xb, nullptr, nullptr, nullptr, gt, nullptr, qb,
               M, sA, sB);
}

__global__ __launch_bounds__(512) void gemm1_kernel(
    const unsigned short* __restrict__ xb, const unsigned short* __restrict__ aggb,
    const unsigned short* __restrict__ tb, const unsigned short* __restrict__ wt,
    float* __restrict__ out, int M) {
  __shared__ __align__(16) unsigned short sA[2 * 128 * 32];
  __shared__ __align__(16) unsigned short sB[2 * 256 * 32];
  gemm_body<1>(blockIdx.x, xb, aggb, tb, wt, nullptr, out, nullptr, M, sA, sB);
}

// ===========================================================================
// Fused gather, masked 8-wide batches (max MLP; avg degree ~6 -> 1 batch).
//   aggb[n] = sum_{csr1(n)} x[s]
//   tb[n]   = -sum_{csr2(n)} (q'[n].x[s]) x[s]
// ===========================================================================
__global__ __launch_bounds__(256) void gather_fused_kernel(
    const unsigned short* __restrict__ xb, const unsigned short* __restrict__ qb,
    const int* __restrict__ off1, const int* __restrict__ csr1,
    const int* __restrict__ off2, const int* __restrict__ csr2,
    int N, unsigned short* __restrict__ aggb, unsigned short* __restrict__ tb) {
  int wid = blockIdx.x * 4 + (threadIdx.x >> 6);
  if (wid >= N) return;
  int lane = threadIdx.x & 63;

  // --- graph 1: agg (masked 8-wide) ---
  {
    int beg = off1[wid], end = off1[wid + 1];
    float ax = 0.f, ay = 0.f, az = 0.f, aw = 0.f;
    for (int j = beg; j < end; j += 8) {
      int e1 = end - 1;
      ushort4 r[8];
      float mk[8];
#pragma unroll
      for (int i = 0; i < 8; i++) {
        int jj = j + i;
        int s = csr1[jj < end ? jj : e1];
        mk[i] = (jj < end) ? 1.f : 0.f;
        r[i] = *reinterpret_cast<const ushort4*>(xb + (size_t)s * TD + lane * 4);
      }
#pragma unroll
      for (int i = 0; i < 8; i++) {
        ax += mk[i] * bf2f(r[i].x);
        ay += mk[i] * bf2f(r[i].y);
        az += mk[i] * bf2f(r[i].z);
        aw += mk[i] * bf2f(r[i].w);
      }
    }
    ushort4 o;
    o.x = f2bf(ax); o.y = f2bf(ay); o.z = f2bf(az); o.w = f2bf(aw);
    *reinterpret_cast<ushort4*>(aggb + (size_t)wid * TD + lane * 4) = o;
  }

  // --- graph 2: t = -sum (q'.x[s]) x[s]  (masked 8-wide, interleaved) ---
  {
    ushort4 qv = *reinterpret_cast<const ushort4*>(qb + (size_t)wid * TD + lane * 4);
    float qx = bf2f(qv.x), qy = bf2f(qv.y), qz = bf2f(qv.z), qw = bf2f(qv.w);
    int beg = off2[wid], end = off2[wid + 1];
    float tx = 0.f, ty = 0.f, tz = 0.f, tw = 0.f;
    for (int j = beg; j < end; j += 8) {
      int e1 = end - 1;
      float vx[8][4];
      float px[8];
#pragma unroll
      for (int i = 0; i < 8; i++) {
        int jj = j + i;
        int s = csr2[jj < end ? jj : e1];
        ushort4 r = *reinterpret_cast<const ushort4*>(xb + (size_t)s * TD + lane * 4);
        vx[i][0] = bf2f(r.x); vx[i][1] = bf2f(r.y);
        vx[i][2] = bf2f(r.z); vx[i][3] = bf2f(r.w);
        px[i] = qx * vx[i][0] + qy * vx[i][1] + qz * vx[i][2] + qw * vx[i][3];
      }
#pragma unroll
      for (int m = 1; m < 64; m <<= 1) {
#pragma unroll
        for (int i = 0; i < 8; i++) px[i] += __shfl_xor(px[i], m, 64);
      }
#pragma unroll
      for (int i = 1; i < 8; i++) px[i] = (j + i < end) ? px[i] : 0.f;
#pragma unroll
      for (int i = 0; i < 8; i++) {
        tx -= px[i] * vx[i][0];
        ty -= px[i] * vx[i][1];
        tz -= px[i] * vx[i][2];
        tw -= px[i] * vx[i][3];
      }
    }
    ushort4 o;
    o.x = f2bf(tx); o.y = f2bf(ty); o.z = f2bf(tz); o.w = f2bf(tw);
    *reinterpret_cast<ushort4*>(tb + (size_t)wid * TD + lane * 4) = o;
  }
}

// ===========================================================================
extern "C" void kernel_launch(void* const* d_in, const int* in_sizes, int n_in,
                              void* d_out, int out_size, void* d_ws,
                              size_t ws_size, hipStream_t stream) {
  const float* x  = (const float*)d_in[0];
  const int*   ei  = (const int*)d_in[1];
  const int*   ei2 = (const int*)d_in[2];
  const float* W0 = (const float*)d_in[3];
  const float* W1 = (const float*)d_in[4];
  const float* Wq = (const float*)d_in[5];
  const float* Wk = (const float*)d_in[6];
  const float* Wv = (const float*)d_in[7];

  const int N  = in_sizes[0] / TD;
  const int E1 = in_sizes[1] / 2;
  const int E2 = in_sizes[2] / 2;

  float* out = (float*)d_out;
  const size_t rowN = (size_t)N * TD;

  // ---- workspace layout ----
  char* p = (char*)d_ws;
  unsigned short* xb   = (unsigned short*)p; p += rowN * 2;
  unsigned short* aggb = (unsigned short*)p; p += rowN * 2;
  unsigned short* qb   = (unsigned short*)p; p += rowN * 2;
  unsigned short* tb   = (unsigned short*)p; p += rowN * 2;
  unsigned short* wt   = (unsigned short*)p; p += 3 * 65536 * 2;  // W0t,W1t,Wvt
  unsigned short* gt   = (unsigned short*)p; p += 65536 * 2;
  unsigned short* wqb  = (unsigned short*)p; p += 65536 * 2;
  unsigned short* wkb  = (unsigned short*)p; p += 65536 * 2;
  int* off1 = (int*)p; p += (N + 1) * 4;
  int* cur1 = (int*)p; p += N * 4;
  int* off2 = (int*)p; p += (N + 1) * 4;
  int* cur2 = (int*)p; p += N * 4;
  int* csr1 = (int*)p; p += (size_t)E1 * 4;
  int* csr2 = (int*)p; p += (size_t)E2 * 4;
  int* deg1 = (int*)p; p += N * 4;
  int* deg2 = (int*)p; p += N * 4;
  int* bsum = (int*)p; p += 512 * 4;

  // 1. zero degree arrays
  hipMemsetAsync(deg1, 0, (size_t)2 * N * sizeof(int), stream);

  // 2. prologue: hist + all dtype conversions in one dispatch
  long total8 = rowN / 8;
  int nbH = 512;
  int nbX = (int)((total8 + 255) / 256);
  prologue_kernel<<<nbH + nbX + 64 + 768, 256, 0, stream>>>(
      ei, E1, ei2, E2, deg1, deg2, x, xb, total8, Wq, Wk, wqb, wkb, W0, W1, Wv,
      wt, nbH, nbX);

  // 3. scan phase A + G = Wq@Wk^T, then fused prefix+fill of off/cur
  scanA_gemmG_kernel<<<516, 256, 0, stream>>>(deg1, deg2, N, bsum, wqb, wkb, gt);
  scan_fill_kernel<<<512, 256, 0, stream>>>(deg1, deg2, bsum, N, off1, cur1,
                                            off2, cur2);

  // 4. CSR fill  ||  q' = x @ G   (independent -> one dispatch)
  int gblk = (N + 127) / 128;
  int FB = 384;
  fill_gemm0_kernel<<<FB + gblk, 512, 0, stream>>>(
      ei, E1, ei2, E2, cur1, cur2, csr1, csr2, xb, gt, qb, N, FB);

  // 5. fused gather: aggb (graph1) + tb (graph2, needs q')
  gather_fused_kernel<<<(N + 3) / 4, 256, 0, stream>>>(xb, qb, off1, csr1,
                                                       off2, csr2, N, aggb, tb);

  // 6. out = x@W0 + agg@W1 + t@Wv   (t already negated)
  gemm1_kernel<<<gblk, 512, 0, stream>>>(xb, aggb, tb, wt, out, N);
}

// Round 11
// 184.645 us; speedup vs baseline: 1.0858x; 1.0858x over previous
//
#include <hip/hip_runtime.h>

#define TD 256  // feature dim

typedef __attribute__((ext_vector_type(8))) short short8;
typedef __attribute__((ext_vector_type(8))) unsigned short ushort8;
typedef __attribute__((ext_vector_type(4))) float f32x4;

__device__ inline unsigned short f2bf(float f) {
  unsigned u = __float_as_uint(f);
  u = u + 0x7fffu + ((u >> 16) & 1u);  // round-to-nearest-even
  return (unsigned short)(u >> 16);
}
__device__ inline float bf2f(unsigned short h) {
  return __uint_as_float(((unsigned)h) << 16);
}

// ===========================================================================
// Prologue mega-kernel: hist | x->bf16 | Wq,Wk row-major bf16 | W0,W1,Wv^T bf16
// ===========================================================================
__global__ __launch_bounds__(256) void prologue_kernel(
    const int* __restrict__ ei, int E1, const int* __restrict__ ei2, int E2,
    int* __restrict__ deg1, int* __restrict__ deg2,
    const float* __restrict__ x, unsigned short* __restrict__ xb, long total8,
    const float* __restrict__ Wq, const float* __restrict__ Wk,
    unsigned short* __restrict__ wqb, unsigned short* __restrict__ wkb,
    const float* __restrict__ W0, const float* __restrict__ W1,
    const float* __restrict__ Wv, unsigned short* __restrict__ wt,
    int nbH, int nbX) {
  int b = blockIdx.x;
  if (b < nbH) {
    int stride = nbH * 256;
    int Emax = max(E1, E2);
    for (int i = b * 256 + threadIdx.x; i < Emax; i += stride) {
      if (i < E1) atomicAdd(&deg1[ei[E1 + i]], 1);
      if (i < E2) atomicAdd(&deg2[ei2[E2 + i]], 1);
    }
  } else if (b < nbH + nbX) {
    long t = (long)(b - nbH) * 256 + threadIdx.x;
    if (t >= total8) return;
    const float4 f0 = *reinterpret_cast<const float4*>(x + t * 8);
    const float4 f1 = *reinterpret_cast<const float4*>(x + t * 8 + 4);
    ushort8 o;
    o[0] = f2bf(f0.x); o[1] = f2bf(f0.y); o[2] = f2bf(f0.z); o[3] = f2bf(f0.w);
    o[4] = f2bf(f1.x); o[5] = f2bf(f1.y); o[6] = f2bf(f1.z); o[7] = f2bf(f1.w);
    *reinterpret_cast<ushort8*>(xb + t * 8) = o;
  } else if (b < nbH + nbX + 64) {
    int t = (b - nbH - nbX) * 256 + threadIdx.x;  // 0..16383
    const float* src = (t < 8192) ? Wq : Wk;
    unsigned short* dst = (t < 8192) ? wqb : wkb;
    int o = (t & 8191) * 8;
    ushort8 r;
#pragma unroll
    for (int j = 0; j < 8; j++) r[j] = f2bf(src[o + j]);
    *reinterpret_cast<ushort8*>(dst + o) = r;
  } else {
    int b2 = b - nbH - nbX - 64;  // 0..767
    int m = b2 >> 8;
    int n = b2 & 255;
    int k = threadIdx.x;
    const float* W = m == 0 ? W0 : m == 1 ? W1 : Wv;
    wt[m * 65536 + n * 256 + k] = f2bf(W[k * 256 + n]);
  }
}

// ===========================================================================
// scan phase A (blocks 0..511) + gemmG (blocks 512..515)
// ===========================================================================
__global__ __launch_bounds__(256) void scanA_gemmG_kernel(
    const int* __restrict__ deg1, const int* __restrict__ deg2, int N,
    int* __restrict__ bsum,
    const unsigned short* __restrict__ wqb, const unsigned short* __restrict__ wkb,
    unsigned short* __restrict__ gt) {
  if (blockIdx.x < 512) {
    int arr = blockIdx.x >> 8;
    int b = blockIdx.x & 255;
    const int* deg = arr ? deg2 : deg1;
    int i = b * 256 + threadIdx.x;
    int v = (i < N) ? deg[i] : 0;
#pragma unroll
    for (int m = 1; m < 64; m <<= 1) v += __shfl_xor(v, m, 64);
    __shared__ int wsum[4];
    if ((threadIdx.x & 63) == 0) wsum[threadIdx.x >> 6] = v;
    __syncthreads();
    if (threadIdx.x == 0)
      bsum[blockIdx.x] = wsum[0] + wsum[1] + wsum[2] + wsum[3];
    return;
  }
  const int t = (blockIdx.x - 512) * 4 + (threadIdx.x >> 6);
  const int l = threadIdx.x & 63;
  const int a0 = (t >> 2) * 64;
  const int b0 = (t & 3) * 64;
  const int lc = l & 15;
  const int lk = l >> 4;
  f32x4 acc[4][4] = {};
#pragma unroll
  for (int ks = 0; ks < 256; ks += 32) {
    const int ko = ks + lk * 8;
    short8 a[4], b[4];
#pragma unroll
    for (int m = 0; m < 4; m++)
      a[m] = *reinterpret_cast<const short8*>(wqb + (a0 + m * 16 + lc) * 256 + ko);
#pragma unroll
    for (int n = 0; n < 4; n++)
      b[n] = *reinterpret_cast<const short8*>(wkb + (b0 + n * 16 + lc) * 256 + ko);
#pragma unroll
    for (int m = 0; m < 4; m++)
#pragma unroll
      for (int n = 0; n < 4; n++)
        acc[m][n] =
            __builtin_amdgcn_mfma_f32_16x16x32_bf16(a[m], b[n], acc[m][n], 0, 0, 0);
  }
#pragma unroll
  for (int m = 0; m < 4; m++)
#pragma unroll
    for (int n = 0; n < 4; n++)
#pragma unroll
      for (int j = 0; j < 4; j++) {
        int a = a0 + m * 16 + lk * 4 + j;
        int b = b0 + n * 16 + lc;
        gt[b * 256 + a] = f2bf(acc[m][n][j]);
      }
}

// ===========================================================================
// scan_fill with in-block bsum prefix.  grid = 512.  bsum = RAW block sums.
// ===========================================================================
__global__ __launch_bounds__(256) void scan_fill_kernel(
    const int* __restrict__ deg1, const int* __restrict__ deg2,
    const int* __restrict__ bsum, int N,
    int* __restrict__ off1, int* __restrict__ cur1,
    int* __restrict__ off2, int* __restrict__ cur2) {
  int arr = blockIdx.x >> 8;
  int b = blockIdx.x & 255;
  const int* deg = arr ? deg2 : deg1;
  int* off = arr ? off2 : off1;
  int* cur = arr ? cur2 : cur1;
  const int t = threadIdx.x;

  __shared__ int redp[4], redt[4];
  int sval = bsum[arr * 256 + t];
  int pv = (t < b) ? sval : 0;
  int tv = sval;
#pragma unroll
  for (int m = 1; m < 64; m <<= 1) {
    pv += __shfl_xor(pv, m, 64);
    tv += __shfl_xor(tv, m, 64);
  }
  if ((t & 63) == 0) { redp[t >> 6] = pv; redt[t >> 6] = tv; }
  __syncthreads();
  int prefix = redp[0] + redp[1] + redp[2] + redp[3];
  int total = redt[0] + redt[1] + redt[2] + redt[3];
  if (b == 255 && t == 0) off[N] = total;

  int i = b * 256 + t;
  __shared__ int sm[256];
  int v = (i < N) ? deg[i] : 0;
  sm[t] = v;
  __syncthreads();
  for (int d = 1; d < 256; d <<= 1) {
    int val = (t >= d) ? sm[t - d] : 0;
    __syncthreads();
    sm[t] += val;
    __syncthreads();
  }
  int e = sm[t] - v + prefix;
  if (i < N) {
    off[i] = e;
    cur[i] = e;
  }
}

__global__ __launch_bounds__(256) void fill_kernel(
    const int* __restrict__ ei, int E1, const int* __restrict__ ei2, int E2,
    int* __restrict__ cur1, int* __restrict__ cur2,
    int* __restrict__ csr1, int* __restrict__ csr2) {
  int stride = gridDim.x * blockDim.x;
  int Emax = max(E1, E2);
  for (int i = blockIdx.x * blockDim.x + threadIdx.x; i < Emax; i += stride) {
    if (i < E1) {
      int d = ei[E1 + i];
      int p = atomicAdd(&cur1[d], 1);
      csr1[p] = ei[i];
    }
    if (i < E2) {
      int d = ei2[E2 + i];
      int p = atomicAdd(&cur2[d], 1);
      csr2[p] = ei2[i];
    }
  }
}

// ===========================================================================
// Fused gather, one wave per (node, graph) pair: gwid = node*2 + graph.
// Halves each wave's serial edge chain, doubles resident waves (TLP).
// Masked 4-wide batches inside (proven round-9 form).
//   graph 0: aggb[n] = sum_{csr1(n)} x[s]
//   graph 1: tb[n]   = -sum_{csr2(n)} (q'[n].x[s]) x[s]
// ===========================================================================
__global__ __launch_bounds__(256) void gather_fused_kernel(
    const unsigned short* __restrict__ xb, const unsigned short* __restrict__ qb,
    const int* __restrict__ off1, const int* __restrict__ csr1,
    const int* __restrict__ off2, const int* __restrict__ csr2,
    int N, unsigned short* __restrict__ aggb, unsigned short* __restrict__ tb) {
  int gwid = blockIdx.x * 4 + (threadIdx.x >> 6);
  int wid = gwid >> 1;
  if (wid >= N) return;
  int lane = threadIdx.x & 63;

  if ((gwid & 1) == 0) {
    // --- graph 1: agg (masked 4-wide) ---
    int beg = off1[wid], end = off1[wid + 1];
    float ax = 0.f, ay = 0.f, az = 0.f, aw = 0.f;
    for (int j = beg; j < end; j += 4) {
      int e1 = end - 1;
      int s0 = csr1[j];
      int s1 = csr1[j + 1 < end ? j + 1 : e1];
      int s2 = csr1[j + 2 < end ? j + 2 : e1];
      int s3 = csr1[j + 3 < end ? j + 3 : e1];
      float m1 = (j + 1 < end) ? 1.f : 0.f;
      float m2 = (j + 2 < end) ? 1.f : 0.f;
      float m3 = (j + 3 < end) ? 1.f : 0.f;
      ushort4 r0 = *reinterpret_cast<const ushort4*>(xb + (size_t)s0 * TD + lane * 4);
      ushort4 r1 = *reinterpret_cast<const ushort4*>(xb + (size_t)s1 * TD + lane * 4);
      ushort4 r2 = *reinterpret_cast<const ushort4*>(xb + (size_t)s2 * TD + lane * 4);
      ushort4 r3 = *reinterpret_cast<const ushort4*>(xb + (size_t)s3 * TD + lane * 4);
      ax += bf2f(r0.x) + m1 * bf2f(r1.x) + m2 * bf2f(r2.x) + m3 * bf2f(r3.x);
      ay += bf2f(r0.y) + m1 * bf2f(r1.y) + m2 * bf2f(r2.y) + m3 * bf2f(r3.y);
      az += bf2f(r0.z) + m1 * bf2f(r1.z) + m2 * bf2f(r2.z) + m3 * bf2f(r3.z);
      aw += bf2f(r0.w) + m1 * bf2f(r1.w) + m2 * bf2f(r2.w) + m3 * bf2f(r3.w);
    }
    ushort4 o;
    o.x = f2bf(ax); o.y = f2bf(ay); o.z = f2bf(az); o.w = f2bf(aw);
    *reinterpret_cast<ushort4*>(aggb + (size_t)wid * TD + lane * 4) = o;
  } else {
    // --- graph 2: t = -sum (q'.x[s]) x[s]  (masked 4-wide, interleaved) ---
    ushort4 qv = *reinterpret_cast<const ushort4*>(qb + (size_t)wid * TD + lane * 4);
    float qx = bf2f(qv.x), qy = bf2f(qv.y), qz = bf2f(qv.z), qw = bf2f(qv.w);
    int beg = off2[wid], end = off2[wid + 1];
    float tx = 0.f, ty = 0.f, tz = 0.f, tw = 0.f;
    for (int j = beg; j < end; j += 4) {
      int e1 = end - 1;
      int s0 = csr2[j];
      int s1 = csr2[j + 1 < end ? j + 1 : e1];
      int s2 = csr2[j + 2 < end ? j + 2 : e1];
      int s3 = csr2[j + 3 < end ? j + 3 : e1];
      ushort4 r0 = *reinterpret_cast<const ushort4*>(xb + (size_t)s0 * TD + lane * 4);
      ushort4 r1 = *reinterpret_cast<const ushort4*>(xb + (size_t)s1 * TD + lane * 4);
      ushort4 r2 = *reinterpret_cast<const ushort4*>(xb + (size_t)s2 * TD + lane * 4);
      ushort4 r3 = *reinterpret_cast<const ushort4*>(xb + (size_t)s3 * TD + lane * 4);
      float a0x = bf2f(r0.x), a0y = bf2f(r0.y), a0z = bf2f(r0.z), a0w = bf2f(r0.w);
      float a1x = bf2f(r1.x), a1y = bf2f(r1.y), a1z = bf2f(r1.z), a1w = bf2f(r1.w);
      float a2x = bf2f(r2.x), a2y = bf2f(r2.y), a2z = bf2f(r2.z), a2w = bf2f(r2.w);
      float a3x = bf2f(r3.x), a3y = bf2f(r3.y), a3z = bf2f(r3.z), a3w = bf2f(r3.w);
      float p0 = qx * a0x + qy * a0y + qz * a0z + qw * a0w;
      float p1 = qx * a1x + qy * a1y + qz * a1z + qw * a1w;
      float p2 = qx * a2x + qy * a2y + qz * a2z + qw * a2w;
      float p3 = qx * a3x + qy * a3y + qz * a3z + qw * a3w;
#pragma unroll
      for (int m = 1; m < 64; m <<= 1) {
        p0 += __shfl_xor(p0, m, 64);
        p1 += __shfl_xor(p1, m, 64);
        p2 += __shfl_xor(p2, m, 64);
        p3 += __shfl_xor(p3, m, 64);
      }
      p1 = (j + 1 < end) ? p1 : 0.f;
      p2 = (j + 2 < end) ? p2 : 0.f;
      p3 = (j + 3 < end) ? p3 : 0.f;
      tx -= p0 * a0x + p1 * a1x + p2 * a2x + p3 * a3x;
      ty -= p0 * a0y + p1 * a1y + p2 * a2y + p3 * a3y;
      tz -= p0 * a0z + p1 * a1z + p2 * a2z + p3 * a3z;
      tw -= p0 * a0w + p1 * a1w + p2 * a2w + p3 * a3w;
    }
    ushort4 o;
    o.x = f2bf(tx); o.y = f2bf(ty); o.z = f2bf(tz); o.w = f2bf(tw);
    *reinterpret_cast<ushort4*>(tb + (size_t)wid * TD + lane * 4) = o;
  }
}

// ===========================================================================
// LDS-staged MFMA GEMM, tile 128x256, 512 thr = 8 waves (2x4 of 64x64).
//   MODE 0: q' = xb @ Gt                    (K=256, bf16 out -> qb)
//   MODE 1: out = xb@W0 + aggb@W1 + tb@Wv   (K=768 segmented, fp32 out)
// KSTEP=64, 16x16x32 bf16 MFMA, global_load_lds(16B) + XOR-(row&7) swizzle.
// (round-5-proven structure; do not modify without isolated A/B)
// ===========================================================================
template <int MODE>
__global__ __launch_bounds__(512) void gemm_lds(
    const unsigned short* __restrict__ xb, const unsigned short* __restrict__ aggb,
    const unsigned short* __restrict__ tb, const unsigned short* __restrict__ wt,
    const unsigned short* __restrict__ gt, float* __restrict__ out,
    unsigned short* __restrict__ qb, int M) {
  __shared__ __align__(16) unsigned short sA[128 * 64];
  __shared__ __align__(16) unsigned short sB[256 * 64];

  const int m0 = blockIdx.x * 128;
  const int tid = threadIdx.x;
  const int w = tid >> 6, l = tid & 63;
  const int lrow = l >> 3, lslot = l & 7;
  const int wr = w >> 2, wc = w & 3;  // 2x4 wave grid, 64x64 each

  f32x4 acc[4][4] = {};

  const int KTOT = (MODE == 0) ? 256 : 768;

  for (int k0 = 0; k0 < KTOT; k0 += 64) {
    const unsigned short* Ap;
    const unsigned short* Bp;
    int ks;
    if (MODE == 0) {
      Ap = xb; Bp = gt; ks = k0;
    } else {
      int seg = k0 >> 8;  // 0: x@W0, 1: agg@W1, 2: t@Wv
      Ap = seg == 0 ? xb : seg == 1 ? aggb : tb;
      Bp = wt + seg * 65536;
      ks = k0 & 255;
    }

    // ---- stage A tile [128][64]: wave w stages rows w*16 .. w*16+15 ----
#pragma unroll
    for (int i = 0; i < 2; i++) {
      int row = w * 16 + i * 8 + lrow;
      int gr = m0 + row;
      if (gr >= M) gr = M - 1;
      int g = lslot ^ lrow;
      const unsigned short* src = Ap + (size_t)gr * TD + ks + g * 8;
      unsigned short* dst = sA + (w * 16 + i * 8) * 64;
      __builtin_amdgcn_global_load_lds(
          (const __attribute__((address_space(1))) void*)src,
          (__attribute__((address_space(3))) void*)dst, 16, 0, 0);
    }
    // ---- stage B tile [256][64]: wave w stages rows w*32 .. w*32+31 ----
#pragma unroll
    for (int i = 0; i < 4; i++) {
      int row = w * 32 + i * 8 + lrow;
      int g = lslot ^ lrow;
      const unsigned short* src = Bp + (size_t)row * TD + ks + g * 8;
      unsigned short* dst = sB + (w * 32 + i * 8) * 64;
      __builtin_amdgcn_global_load_lds(
          (const __attribute__((address_space(1))) void*)src,
          (__attribute__((address_space(3))) void*)dst, 16, 0, 0);
    }
    __syncthreads();

#pragma unroll
    for (int kk = 0; kk < 2; kk++) {
      short8 a[4], b[4];
#pragma unroll
      for (int m = 0; m < 4; m++) {
        int row = wr * 64 + m * 16 + (l & 15);
        int slot = (kk * 4 + (l >> 4)) ^ (row & 7);
        a[m] = *reinterpret_cast<const short8*>(&sA[row * 64 + slot * 8]);
      }
#pragma unroll
      for (int n = 0; n < 4; n++) {
        int row = wc * 64 + n * 16 + (l & 15);
        int slot = (kk * 4 + (l >> 4)) ^ (row & 7);
        b[n] = *reinterpret_cast<const short8*>(&sB[row * 64 + slot * 8]);
      }
#pragma unroll
      for (int m = 0; m < 4; m++)
#pragma unroll
        for (int n = 0; n < 4; n++)
          acc[m][n] =
              __builtin_amdgcn_mfma_f32_16x16x32_bf16(a[m], b[n], acc[m][n], 0, 0, 0);
    }
    __syncthreads();
  }

  // ---- store ----
  if (MODE == 1) {
#pragma unroll
    for (int m = 0; m < 4; m++)
#pragma unroll
      for (int n = 0; n < 4; n++)
#pragma unroll
        for (int j = 0; j < 4; j++) {
          int r = m0 + wr * 64 + m * 16 + (l >> 4) * 4 + j;
          if (r < M)
            out[(size_t)r * TD + wc * 64 + n * 16 + (l & 15)] = acc[m][n][j];
        }
  } else {
#pragma unroll
    for (int m = 0; m < 4; m++)
#pragma unroll
      for (int n = 0; n < 4; n++)
#pragma unroll
        for (int j = 0; j < 4; j++) {
          int r = m0 + wr * 64 + m * 16 + (l >> 4) * 4 + j;
          if (r < M)
            qb[(size_t)r * TD + wc * 64 + n * 16 + (l & 15)] =
                f2bf(acc[m][n][j]);
        }
  }
}

// ===========================================================================
extern "C" void kernel_launch(void* const* d_in, const int* in_sizes, int n_in,
                              void* d_out, int out_size, void* d_ws,
                              size_t ws_size, hipStream_t stream) {
  const float* x  = (const float*)d_in[0];
  const int*   ei  = (const int*)d_in[1];
  const int*   ei2 = (const int*)d_in[2];
  const float* W0 = (const float*)d_in[3];
  const float* W1 = (const float*)d_in[4];
  const float* Wq = (const float*)d_in[5];
  const float* Wk = (const float*)d_in[6];
  const float* Wv = (const float*)d_in[7];

  const int N  = in_sizes[0] / TD;
  const int E1 = in_sizes[1] / 2;
  const int E2 = in_sizes[2] / 2;

  float* out = (float*)d_out;
  const size_t rowN = (size_t)N * TD;

  // ---- workspace layout ----
  char* p = (char*)d_ws;
  unsigned short* xb   = (unsigned short*)p; p += rowN * 2;
  unsigned short* aggb = (unsigned short*)p; p += rowN * 2;
  unsigned short* qb   = (unsigned short*)p; p += rowN * 2;
  unsigned short* tb   = (unsigned short*)p; p += rowN * 2;
  unsigned short* wt   = (unsigned short*)p; p += 3 * 65536 * 2;  // W0t,W1t,Wvt
  unsigned short* gt   = (unsigned short*)p; p += 65536 * 2;
  unsigned short* wqb  = (unsigned short*)p; p += 65536 * 2;
  unsigned short* wkb  = (unsigned short*)p; p += 65536 * 2;
  int* off1 = (int*)p; p += (N + 1) * 4;
  int* cur1 = (int*)p; p += N * 4;
  int* off2 = (int*)p; p += (N + 1) * 4;
  int* cur2 = (int*)p; p += N * 4;
  int* csr1 = (int*)p; p += (size_t)E1 * 4;
  int* csr2 = (int*)p; p += (size_t)E2 * 4;
  int* deg1 = (int*)p; p += N * 4;
  int* deg2 = (int*)p; p += N * 4;
  int* bsum = (int*)p; p += 512 * 4;

  // 1. zero degree arrays
  hipMemsetAsync(deg1, 0, (size_t)2 * N * sizeof(int), stream);

  // 2. prologue: hist + all dtype conversions in one dispatch
  long total8 = rowN / 8;
  int nbH = 512;
  int nbX = (int)((total8 + 255) / 256);
  prologue_kernel<<<nbH + nbX + 64 + 768, 256, 0, stream>>>(
      ei, E1, ei2, E2, deg1, deg2, x, xb, total8, Wq, Wk, wqb, wkb, W0, W1, Wv,
      wt, nbH, nbX);

  // 3. scan phase A + G = Wq@Wk^T, then fused prefix+fill of off/cur
  scanA_gemmG_kernel<<<516, 256, 0, stream>>>(deg1, deg2, N, bsum, wqb, wkb, gt);
  scan_fill_kernel<<<512, 256, 0, stream>>>(deg1, deg2, bsum, N, off1, cur1,
                                            off2, cur2);
  fill_kernel<<<1024, 256, 0, stream>>>(ei, E1, ei2, E2, cur1, cur2, csr1, csr2);

  // 4. q' = x @ G
  int gblk = (N + 127) / 128;
  gemm_lds<0><<<gblk, 512, 0, stream>>>(xb, aggb, tb, wt, gt, out, qb, N);

  // 5. fused gather: one wave per (node, graph)
  gather_fused_kernel<<<(2 * N + 3) / 4, 256, 0, stream>>>(
      xb, qb, off1, csr1, off2, csr2, N, aggb, tb);

  // 6. out = x@W0 + agg@W1 + t@Wv   (t already negated)
  gemm_lds<1><<<gblk, 512, 0, stream>>>(xb, aggb, tb, wt, gt, out, qb, N);
}

// Round 13
// 179.021 us; speedup vs baseline: 1.1199x; 1.0314x over previous
//
#include <hip/hip_runtime.h>

#define TD 256  // feature dim

typedef __attribute__((ext_vector_type(8))) short short8;
typedef __attribute__((ext_vector_type(8))) unsigned short ushort8;
typedef __attribute__((ext_vector_type(4))) float f32x4;

__device__ inline unsigned short f2bf(float f) {
  unsigned u = __float_as_uint(f);
  u = u + 0x7fffu + ((u >> 16) & 1u);  // round-to-nearest-even
  return (unsigned short)(u >> 16);
}
__device__ inline float bf2f(unsigned short h) {
  return __uint_as_float(((unsigned)h) << 16);
}

// ===========================================================================
// Prologue mega-kernel: hist | x->bf16 | Wq,Wk row-major bf16 | W0,W1,Wv^T bf16
// ===========================================================================
__global__ __launch_bounds__(256) void prologue_kernel(
    const int* __restrict__ ei, int E1, const int* __restrict__ ei2, int E2,
    int* __restrict__ deg1, int* __restrict__ deg2,
    const float* __restrict__ x, unsigned short* __restrict__ xb, long total8,
    const float* __restrict__ Wq, const float* __restrict__ Wk,
    unsigned short* __restrict__ wqb, unsigned short* __restrict__ wkb,
    const float* __restrict__ W0, const float* __restrict__ W1,
    const float* __restrict__ Wv, unsigned short* __restrict__ wt,
    int nbH, int nbX) {
  int b = blockIdx.x;
  if (b < nbH) {
    int stride = nbH * 256;
    int Emax = max(E1, E2);
    for (int i = b * 256 + threadIdx.x; i < Emax; i += stride) {
      if (i < E1) atomicAdd(&deg1[ei[E1 + i]], 1);
      if (i < E2) atomicAdd(&deg2[ei2[E2 + i]], 1);
    }
  } else if (b < nbH + nbX) {
    long t = (long)(b - nbH) * 256 + threadIdx.x;
    if (t >= total8) return;
    const float4 f0 = *reinterpret_cast<const float4*>(x + t * 8);
    const float4 f1 = *reinterpret_cast<const float4*>(x + t * 8 + 4);
    ushort8 o;
    o[0] = f2bf(f0.x); o[1] = f2bf(f0.y); o[2] = f2bf(f0.z); o[3] = f2bf(f0.w);
    o[4] = f2bf(f1.x); o[5] = f2bf(f1.y); o[6] = f2bf(f1.z); o[7] = f2bf(f1.w);
    *reinterpret_cast<ushort8*>(xb + t * 8) = o;
  } else if (b < nbH + nbX + 64) {
    int t = (b - nbH - nbX) * 256 + threadIdx.x;  // 0..16383
    const float* src = (t < 8192) ? Wq : Wk;
    unsigned short* dst = (t < 8192) ? wqb : wkb;
    int o = (t & 8191) * 8;
    ushort8 r;
#pragma unroll
    for (int j = 0; j < 8; j++) r[j] = f2bf(src[o + j]);
    *reinterpret_cast<ushort8*>(dst + o) = r;
  } else {
    int b2 = b - nbH - nbX - 64;  // 0..767
    int m = b2 >> 8;
    int n = b2 & 255;
    int k = threadIdx.x;
    const float* W = m == 0 ? W0 : m == 1 ? W1 : Wv;
    wt[m * 65536 + n * 256 + k] = f2bf(W[k * 256 + n]);
  }
}

// ===========================================================================
// scan phase A (blocks 0..511) + gemmG (blocks 512..515)
// ===========================================================================
__global__ __launch_bounds__(256) void scanA_gemmG_kernel(
    const int* __restrict__ deg1, const int* __restrict__ deg2, int N,
    int* __restrict__ bsum,
    const unsigned short* __restrict__ wqb, const unsigned short* __restrict__ wkb,
    unsigned short* __restrict__ gt) {
  if (blockIdx.x < 512) {
    int arr = blockIdx.x >> 8;
    int b = blockIdx.x & 255;
    const int* deg = arr ? deg2 : deg1;
    int i = b * 256 + threadIdx.x;
    int v = (i < N) ? deg[i] : 0;
#pragma unroll
    for (int m = 1; m < 64; m <<= 1) v += __shfl_xor(v, m, 64);
    __shared__ int wsum[4];
    if ((threadIdx.x & 63) == 0) wsum[threadIdx.x >> 6] = v;
    __syncthreads();
    if (threadIdx.x == 0)
      bsum[blockIdx.x] = wsum[0] + wsum[1] + wsum[2] + wsum[3];
    return;
  }
  const int t = (blockIdx.x - 512) * 4 + (threadIdx.x >> 6);
  const int l = threadIdx.x & 63;
  const int a0 = (t >> 2) * 64;
  const int b0 = (t & 3) * 64;
  const int lc = l & 15;
  const int lk = l >> 4;
  f32x4 acc[4][4] = {};
#pragma unroll
  for (int ks = 0; ks < 256; ks += 32) {
    const int ko = ks + lk * 8;
    short8 a[4], b[4];
#pragma unroll
    for (int m = 0; m < 4; m++)
      a[m] = *reinterpret_cast<const short8*>(wqb + (a0 + m * 16 + lc) * 256 + ko);
#pragma unroll
    for (int n = 0; n < 4; n++)
      b[n] = *reinterpret_cast<const short8*>(wkb + (b0 + n * 16 + lc) * 256 + ko);
#pragma unroll
    for (int m = 0; m < 4; m++)
#pragma unroll
      for (int n = 0; n < 4; n++)
        acc[m][n] =
            __builtin_amdgcn_mfma_f32_16x16x32_bf16(a[m], b[n], acc[m][n], 0, 0, 0);
  }
#pragma unroll
  for (int m = 0; m < 4; m++)
#pragma unroll
    for (int n = 0; n < 4; n++)
#pragma unroll
      for (int j = 0; j < 4; j++) {
        int a = a0 + m * 16 + lk * 4 + j;
        int b = b0 + n * 16 + lc;
        gt[b * 256 + a] = f2bf(acc[m][n][j]);
      }
}

// ===========================================================================
// scan_fill with in-block bsum prefix.  grid = 512.  bsum = RAW block sums.
// ===========================================================================
__global__ __launch_bounds__(256) void scan_fill_kernel(
    const int* __restrict__ deg1, const int* __restrict__ deg2,
    const int* __restrict__ bsum, int N,
    int* __restrict__ off1, int* __restrict__ cur1,
    int* __restrict__ off2, int* __restrict__ cur2) {
  int arr = blockIdx.x >> 8;
  int b = blockIdx.x & 255;
  const int* deg = arr ? deg2 : deg1;
  int* off = arr ? off2 : off1;
  int* cur = arr ? cur2 : cur1;
  const int t = threadIdx.x;

  __shared__ int redp[4], redt[4];
  int sval = bsum[arr * 256 + t];
  int pv = (t < b) ? sval : 0;
  int tv = sval;
#pragma unroll
  for (int m = 1; m < 64; m <<= 1) {
    pv += __shfl_xor(pv, m, 64);
    tv += __shfl_xor(tv, m, 64);
  }
  if ((t & 63) == 0) { redp[t >> 6] = pv; redt[t >> 6] = tv; }
  __syncthreads();
  int prefix = redp[0] + redp[1] + redp[2] + redp[3];
  int total = redt[0] + redt[1] + redt[2] + redt[3];
  if (b == 255 && t == 0) off[N] = total;

  int i = b * 256 + t;
  __shared__ int sm[256];
  int v = (i < N) ? deg[i] : 0;
  sm[t] = v;
  __syncthreads();
  for (int d = 1; d < 256; d <<= 1) {
    int val = (t >= d) ? sm[t - d] : 0;
    __syncthreads();
    sm[t] += val;
    __syncthreads();
  }
  int e = sm[t] - v + prefix;
  if (i < N) {
    off[i] = e;
    cur[i] = e;
  }
}

// ===========================================================================
// Merged: blocks [0,FB) do CSR fill; blocks [FB, FB+gblk) do gemm0 (q'=x@Gt),
// using the round-5-proven KSTEP=64 / XOR-(row&7) GEMM body UNCHANGED.
// ===========================================================================
__global__ __launch_bounds__(512) void fill_gemm0_kernel(
    const int* __restrict__ ei, int E1, const int* __restrict__ ei2, int E2,
    int* __restrict__ cur1, int* __restrict__ cur2,
    int* __restrict__ csr1, int* __restrict__ csr2,
    const unsigned short* __restrict__ xb, const unsigned short* __restrict__ gt,
    unsigned short* __restrict__ qb, int M, int FB) {
  __shared__ __align__(16) unsigned short sA[128 * 64];
  __shared__ __align__(16) unsigned short sB[256 * 64];

  if (blockIdx.x < FB) {
    int stride = FB * 512;
    int Emax = max(E1, E2);
    for (int i = blockIdx.x * 512 + threadIdx.x; i < Emax; i += stride) {
      if (i < E1) {
        int d = ei[E1 + i];
        int p = atomicAdd(&cur1[d], 1);
        csr1[p] = ei[i];
      }
      if (i < E2) {
        int d = ei2[E2 + i];
        int p = atomicAdd(&cur2[d], 1);
        csr2[p] = ei2[i];
      }
    }
    return;
  }

  const int m0 = (blockIdx.x - FB) * 128;
  const int tid = threadIdx.x;
  const int w = tid >> 6, l = tid & 63;
  const int lrow = l >> 3, lslot = l & 7;
  const int wr = w >> 2, wc = w & 3;  // 2x4 wave grid, 64x64 each

  f32x4 acc[4][4] = {};

  for (int k0 = 0; k0 < 256; k0 += 64) {
    const unsigned short* Ap = xb;
    const unsigned short* Bp = gt;
    int ks = k0;

#pragma unroll
    for (int i = 0; i < 2; i++) {
      int row = w * 16 + i * 8 + lrow;
      int gr = m0 + row;
      if (gr >= M) gr = M - 1;
      int g = lslot ^ lrow;
      const unsigned short* src = Ap + (size_t)gr * TD + ks + g * 8;
      unsigned short* dst = sA + (w * 16 + i * 8) * 64;
      __builtin_amdgcn_global_load_lds(
          (const __attribute__((address_space(1))) void*)src,
          (__attribute__((address_space(3))) void*)dst, 16, 0, 0);
    }
#pragma unroll
    for (int i = 0; i < 4; i++) {
      int row = w * 32 + i * 8 + lrow;
      int g = lslot ^ lrow;
      const unsigned short* src = Bp + (size_t)row * TD + ks + g * 8;
      unsigned short* dst = sB + (w * 32 + i * 8) * 64;
      __builtin_amdgcn_global_load_lds(
          (const __attribute__((address_space(1))) void*)src,
          (__attribute__((address_space(3))) void*)dst, 16, 0, 0);
    }
    __syncthreads();

#pragma unroll
    for (int kk = 0; kk < 2; kk++) {
      short8 a[4], b[4];
#pragma unroll
      for (int m = 0; m < 4; m++) {
        int row = wr * 64 + m * 16 + (l & 15);
        int slot = (kk * 4 + (l >> 4)) ^ (row & 7);
        a[m] = *reinterpret_cast<const short8*>(&sA[row * 64 + slot * 8]);
      }
#pragma unroll
      for (int n = 0; n < 4; n++) {
        int row = wc * 64 + n * 16 + (l & 15);
        int slot = (kk * 4 + (l >> 4)) ^ (row & 7);
        b[n] = *reinterpret_cast<const short8*>(&sB[row * 64 + slot * 8]);
      }
#pragma unroll
      for (int m = 0; m < 4; m++)
#pragma unroll
        for (int n = 0; n < 4; n++)
          acc[m][n] =
              __builtin_amdgcn_mfma_f32_16x16x32_bf16(a[m], b[n], acc[m][n], 0, 0, 0);
    }
    __syncthreads();
  }

#pragma unroll
  for (int m = 0; m < 4; m++)
#pragma unroll
    for (int n = 0; n < 4; n++)
#pragma unroll
      for (int j = 0; j < 4; j++) {
        int r = m0 + wr * 64 + m * 16 + (l >> 4) * 4 + j;
        if (r < M)
          qb[(size_t)r * TD + wc * 64 + n * 16 + (l & 15)] = f2bf(acc[m][n][j]);
      }
}

// ===========================================================================
// Fused gather: one wave per node; TWO edges processed concurrently by the
// two 32-lane halves (eh = lane>>5).  Each lane holds 8 dims (ushort8, 16B).
// Score reduce = 5 shfl_xor steps within a half (serves 2 edges at once).
// 2-wide batch -> 4 edges in flight.  Final 8-shfl half-combine per node.
//   aggb[n] = sum_{csr1(n)} x[s]
//   tb[n]   = -sum_{csr2(n)} (q'[n].x[s]) x[s]
// ===========================================================================
__global__ __launch_bounds__(256) void gather_fused_kernel(
    const unsigned short* __restrict__ xb, const unsigned short* __restrict__ qb,
    const int* __restrict__ off1, const int* __restrict__ csr1,
    const int* __restrict__ off2, const int* __restrict__ csr2,
    int N, unsigned short* __restrict__ aggb, unsigned short* __restrict__ tb) {
  int wid = blockIdx.x * 4 + (threadIdx.x >> 6);
  if (wid >= N) return;
  const int lane = threadIdx.x & 63;
  const int eh = lane >> 5;   // edge half 0/1
  const int sl = lane & 31;   // sub-lane: dims [sl*8, sl*8+8)

  // --- graph 1: agg ---
  {
    int beg = off1[wid], end = off1[wid + 1];
    float acc[8] = {};
    for (int j = beg; j < end; j += 4) {
      int e1 = end - 1;
      int j0 = j + eh, j1 = j + 2 + eh;
      int s0 = csr1[j0 < end ? j0 : e1];
      int s1 = csr1[j1 < end ? j1 : e1];
      float k0 = (j0 < end) ? 1.f : 0.f;
      float k1 = (j1 < end) ? 1.f : 0.f;
      ushort8 r0 = *reinterpret_cast<const ushort8*>(xb + (size_t)s0 * TD + sl * 8);
      ushort8 r1 = *reinterpret_cast<const ushort8*>(xb + (size_t)s1 * TD + sl * 8);
#pragma unroll
      for (int i = 0; i < 8; i++)
        acc[i] += k0 * bf2f(r0[i]) + k1 * bf2f(r1[i]);
    }
#pragma unroll
    for (int i = 0; i < 8; i++) acc[i] += __shfl_xor(acc[i], 32, 64);
    if (eh == 0) {
      ushort8 o;
#pragma unroll
      for (int i = 0; i < 8; i++) o[i] = f2bf(acc[i]);
      *reinterpret_cast<ushort8*>(aggb + (size_t)wid * TD + sl * 8) = o;
    }
  }

  // --- graph 2: t = -sum (q'.x[s]) x[s] ---
  {
    ushort8 qv = *reinterpret_cast<const ushort8*>(qb + (size_t)wid * TD + sl * 8);
    float q[8];
#pragma unroll
    for (int i = 0; i < 8; i++) q[i] = bf2f(qv[i]);
    int beg = off2[wid], end = off2[wid + 1];
    float t[8] = {};
    for (int j = beg; j < end; j += 4) {
      int e1 = end - 1;
      int j0 = j + eh, j1 = j + 2 + eh;
      int s0 = csr2[j0 < end ? j0 : e1];
      int s1 = csr2[j1 < end ? j1 : e1];
      float k0 = (j0 < end) ? 1.f : 0.f;
      float k1 = (j1 < end) ? 1.f : 0.f;
      ushort8 r0 = *reinterpret_cast<const ushort8*>(xb + (size_t)s0 * TD + sl * 8);
      ushort8 r1 = *reinterpret_cast<const ushort8*>(xb + (size_t)s1 * TD + sl * 8);
      float x0[8], x1[8];
      float p0 = 0.f, p1 = 0.f;
#pragma unroll
      for (int i = 0; i < 8; i++) {
        x0[i] = bf2f(r0[i]); x1[i] = bf2f(r1[i]);
        p0 += q[i] * x0[i];  p1 += q[i] * x1[i];
      }
#pragma unroll
      for (int m = 1; m < 32; m <<= 1) {
        p0 += __shfl_xor(p0, m, 64);
        p1 += __shfl_xor(p1, m, 64);
      }
      p0 *= k0; p1 *= k1;
#pragma unroll
      for (int i = 0; i < 8; i++) t[i] -= p0 * x0[i] + p1 * x1[i];
    }
#pragma unroll
    for (int i = 0; i < 8; i++) t[i] += __shfl_xor(t[i], 32, 64);
    if (eh == 0) {
      ushort8 o;
#pragma unroll
      for (int i = 0; i < 8; i++) o[i] = f2bf(t[i]);
      *reinterpret_cast<ushort8*>(tb + (size_t)wid * TD + sl * 8) = o;
    }
  }
}

// ===========================================================================
// LDS-staged MFMA GEMM, tile 128x256, 512 thr = 8 waves (2x4 of 64x64).
//   out = xb@W0 + aggb@W1 + tb@Wv   (K=768 segmented, fp32 out)
// KSTEP=64, 16x16x32 bf16 MFMA, global_load_lds(16B) + XOR-(row&7) swizzle.
// (round-5-proven structure; do not modify without isolated A/B)
// ===========================================================================
__global__ __launch_bounds__(512) void gemm1_kernel(
    const unsigned short* __restrict__ xb, const unsigned short* __restrict__ aggb,
    const unsigned short* __restrict__ tb, const unsigned short* __restrict__ wt,
    float* __restrict__ out, int M) {
  __shared__ __align__(16) unsigned short sA[128 * 64];
  __shared__ __align__(16) unsigned short sB[256 * 64];

  const int m0 = blockIdx.x * 128;
  const int tid = threadIdx.x;
  const int w = tid >> 6, l = tid & 63;
  const int lrow = l >> 3, lslot = l & 7;
  const int wr = w >> 2, wc = w & 3;

  f32x4 acc[4][4] = {};

  for (int k0 = 0; k0 < 768; k0 += 64) {
    int seg = k0 >> 8;  // 0: x@W0, 1: agg@W1, 2: t@Wv
    const unsigned short* Ap = seg == 0 ? xb : seg == 1 ? aggb : tb;
    const unsigned short* Bp = wt + seg * 65536;
    int ks = k0 & 255;

#pragma unroll
    for (int i = 0; i < 2; i++) {
      int row = w * 16 + i * 8 + lrow;
      int gr = m0 + row;
      if (gr >= M) gr = M - 1;
      int g = lslot ^ lrow;
      const unsigned short* src = Ap + (size_t)gr * TD + ks + g * 8;
      unsigned short* dst = sA + (w * 16 + i * 8) * 64;
      __builtin_amdgcn_global_load_lds(
          (const __attribute__((address_space(1))) void*)src,
          (__attribute__((address_space(3))) void*)dst, 16, 0, 0);
    }
#pragma unroll
    for (int i = 0; i < 4; i++) {
      int row = w * 32 + i * 8 + lrow;
      int g = lslot ^ lrow;
      const unsigned short* src = Bp + (size_t)row * TD + ks + g * 8;
      unsigned short* dst = sB + (w * 32 + i * 8) * 64;
      __builtin_amdgcn_global_load_lds(
          (const __attribute__((address_space(1))) void*)src,
          (__attribute__((address_space(3))) void*)dst, 16, 0, 0);
    }
    __syncthreads();

#pragma unroll
    for (int kk = 0; kk < 2; kk++) {
      short8 a[4], b[4];
#pragma unroll
      for (int m = 0; m < 4; m++) {
        int row = wr * 64 + m * 16 + (l & 15);
        int slot = (kk * 4 + (l >> 4)) ^ (row & 7);
        a[m] = *reinterpret_cast<const short8*>(&sA[row * 64 + slot * 8]);
      }
#pragma unroll
      for (int n = 0; n < 4; n++) {
        int row = wc * 64 + n * 16 + (l & 15);
        int slot = (kk * 4 + (l >> 4)) ^ (row & 7);
        b[n] = *reinterpret_cast<const short8*>(&sB[row * 64 + slot * 8]);
      }
#pragma unroll
      for (int m = 0; m < 4; m++)
#pragma unroll
        for (int n = 0; n < 4; n++)
          acc[m][n] =
              __builtin_amdgcn_mfma_f32_16x16x32_bf16(a[m], b[n], acc[m][n], 0, 0, 0);
    }
    __syncthreads();
  }

#pragma unroll
  for (int m = 0; m < 4; m++)
#pragma unroll
    for (int n = 0; n < 4; n++)
#pragma unroll
      for (int j = 0; j < 4; j++) {
        int r = m0 + wr * 64 + m * 16 + (l >> 4) * 4 + j;
        if (r < M)
          out[(size_t)r * TD + wc * 64 + n * 16 + (l & 15)] = acc[m][n][j];
      }
}

// ===========================================================================
extern "C" void kernel_launch(void* const* d_in, const int* in_sizes, int n_in,
                              void* d_out, int out_size, void* d_ws,
                              size_t ws_size, hipStream_t stream) {
  const float* x  = (const float*)d_in[0];
  const int*   ei  = (const int*)d_in[1];
  const int*   ei2 = (const int*)d_in[2];
  const float* W0 = (const float*)d_in[3];
  const float* W1 = (const float*)d_in[4];
  const float* Wq = (const float*)d_in[5];
  const float* Wk = (const float*)d_in[6];
  const float* Wv = (const float*)d_in[7];

  const int N  = in_sizes[0] / TD;
  const int E1 = in_sizes[1] / 2;
  const int E2 = in_sizes[2] / 2;

  float* out = (float*)d_out;
  const size_t rowN = (size_t)N * TD;

  // ---- workspace layout ----
  char* p = (char*)d_ws;
  unsigned short* xb   = (unsigned short*)p; p += rowN * 2;
  unsigned short* aggb = (unsigned short*)p; p += rowN * 2;
  unsigned short* qb   = (unsigned short*)p; p += rowN * 2;
  unsigned short* tb   = (unsigned short*)p; p += rowN * 2;
  unsigned short* wt   = (unsigned short*)p; p += 3 * 65536 * 2;  // W0t,W1t,Wvt
  unsigned short* gt   = (unsigned short*)p; p += 65536 * 2;
  unsigned short* wqb  = (unsigned short*)p; p += 65536 * 2;
  unsigned short* wkb  = (unsigned short*)p; p += 65536 * 2;
  int* off1 = (int*)p; p += (N + 1) * 4;
  int* cur1 = (int*)p; p += N * 4;
  int* off2 = (int*)p; p += (N + 1) * 4;
  int* cur2 = (int*)p; p += N * 4;
  int* csr1 = (int*)p; p += (size_t)E1 * 4;
  int* csr2 = (int*)p; p += (size_t)E2 * 4;
  int* deg1 = (int*)p; p += N * 4;
  int* deg2 = (int*)p; p += N * 4;
  int* bsum = (int*)p; p += 512 * 4;

  // 1. zero degree arrays
  hipMemsetAsync(deg1, 0, (size_t)2 * N * sizeof(int), stream);

  // 2. prologue: hist + all dtype conversions in one dispatch
  long total8 = rowN / 8;
  int nbH = 512;
  int nbX = (int)((total8 + 255) / 256);
  prologue_kernel<<<nbH + nbX + 64 + 768, 256, 0, stream>>>(
      ei, E1, ei2, E2, deg1, deg2, x, xb, total8, Wq, Wk, wqb, wkb, W0, W1, Wv,
      wt, nbH, nbX);

  // 3. scan phase A + G = Wq@Wk^T, then fused prefix+fill of off/cur
  scanA_gemmG_kernel<<<516, 256, 0, stream>>>(deg1, deg2, N, bsum, wqb, wkb, gt);
  scan_fill_kernel<<<512, 256, 0, stream>>>(deg1, deg2, bsum, N, off1, cur1,
                                            off2, cur2);

  // 4. CSR fill  ||  q' = x @ G  (proven GEMM body, merged dispatch)
  int gblk = (N + 127) / 128;
  int FB = 384;
  fill_gemm0_kernel<<<FB + gblk, 512, 0, stream>>>(
      ei, E1, ei2, E2, cur1, cur2, csr1, csr2, xb, gt, qb, N, FB);

  // 5. fused gather: 2 edges per wave via 32-lane halves, 16B/lane
  gather_fused_kernel<<<(N + 3) / 4, 256, 0, stream>>>(xb, qb, off1, csr1,
                                                       off2, csr2, N, aggb, tb);

  // 6. out = x@W0 + agg@W1 + t@Wv   (t already negated)
  gemm1_kernel<<<gblk, 512, 0, stream>>>(xb, aggb, tb, wt, out, N);
}